// Round 11
// baseline (1236.998 us; speedup 1.0000x reference)
//
#include <hip/hip_runtime.h>
#include <hip/hip_bf16.h>

#pragma clang fp contract(off)

typedef unsigned long long ull;

// ---------- numeric helpers (rounding-faithful to reference) ----------
__device__ __forceinline__ float lrelu(float v) { return v >= 0.0f ? v : 0.1f * v; }

__device__ __forceinline__ float sumsq3(float x, float y, float z) {
    return ((x * x) + (y * y)) + (z * z);
}

__device__ __forceinline__ float dot3fma(float ax, float ay, float az,
                                         float bx, float by, float bz) {
    float d = ax * bx;
    d = __builtin_fmaf(ay, by, d);
    d = __builtin_fmaf(az, bz, d);
    return d;
}

// d = (qn+sn) - 2*dot with one rounding (2*dot exact) == fma(-2, dot, s)
__device__ __forceinline__ float distf(float qn, float sn, float dot) {
    float s = qn + sn;
    return __builtin_fmaf(-2.0f, dot, s);
}

// monotone key: integer compare on key == lexicographic (d, idx) compare
__device__ __forceinline__ ull packkey(float d, int i) {
    unsigned u = __float_as_uint(d);
    u = (u & 0x80000000u) ? ~u : (u | 0x80000000u);
    return ((ull)u << 32) | (unsigned)i;
}

__device__ __forceinline__ ull shfl_xor_u64(ull v, int mask) {
    int lo = __shfl_xor((int)(v & 0xffffffffull), mask);
    int hi = __shfl_xor((int)(v >> 32), mask);
    return ((ull)(unsigned)hi << 32) | (unsigned)lo;
}

__device__ __forceinline__ void cswap64(ull& x, ull& y) {
    bool sw = y < x;
    ull lo = sw ? y : x;
    ull hi = sw ? x : y;
    x = lo; y = hi;
}

__device__ __forceinline__ ull min64(ull a, ull b) { return a < b ? a : b; }

// ---------- kernel 1: pre-MLP ----------
__global__ void k_pre(const float* __restrict__ feat, const float* __restrict__ W,
                      const float* __restrict__ g, const float* __restrict__ bb,
                      float* __restrict__ x0) {
    int p = blockIdx.x * blockDim.x + threadIdx.x;
    if (p >= 2 * 8192) return;
    const float* f = feat + (size_t)p * 6;
    float fv[6];
#pragma unroll
    for (int c = 0; c < 6; ++c) fv[c] = f[c];
    float* out = x0 + (size_t)p * 64;
    for (int o = 0; o < 64; ++o) {
        float s = 0.0f;
#pragma unroll
        for (int c = 0; c < 6; ++c) s = __builtin_fmaf(W[o * 6 + c], fv[c], s);
        float v = s * g[o];
        v = v + bb[o];
        out[o] = lrelu(v);
    }
}

// ---------- kernel 2: weight transpose W[M][K] -> WT[K][M] ----------
__global__ void k_wt(const float* __restrict__ W, float* __restrict__ WT, int M, int K) {
    int i = blockIdx.x * 256 + threadIdx.x;
    if (i >= M * K) return;
    int o = i / K, c = i - o * K;
    WT[c * M + o] = W[i];
}

// ---------- kernel 3: KNN via pending-buffer + exact tau pruning ----------
template <int LPQ, int TS>
__launch_bounds__(256)
__global__ void k_knn_reg(const float* __restrict__ xyz, int* __restrict__ out_idx, int Npts) {
    constexpr int QPB = 256 / LPQ;
    __shared__ float4 sp[TS];
    int b = blockIdx.y;
    int tid = threadIdx.x;
    int qi = tid / LPQ;
    int l = tid % LPQ;
    int q = blockIdx.x * QPB + qi;
    const float* X = xyz + (size_t)b * Npts * 3;
    float qx = X[q * 3], qy = X[q * 3 + 1], qz = X[q * 3 + 2];
    float qn = sumsq3(qx, qy, qz);

    ull key[16];
#pragma unroll
    for (int u = 0; u < 16; ++u) key[u] = ~0ull;
    ull p0 = ~0ull, p1 = ~0ull, p2 = ~0ull, p3 = ~0ull;
    int cnt = 0;
    float tau_d = INFINITY;

    auto merge = [&]() {
        cswap64(p0, p2); cswap64(p1, p3); cswap64(p0, p1);
        cswap64(p2, p3); cswap64(p1, p2);
        key[12] = min64(key[12], p3);
        key[13] = min64(key[13], p2);
        key[14] = min64(key[14], p1);
        key[15] = min64(key[15], p0);
#pragma unroll
        for (int dstep = 8; dstep >= 1; dstep >>= 1) {
#pragma unroll
            for (int i = 0; i < 16; ++i) {
                if (!(i & dstep)) cswap64(key[i], key[i + dstep]);
            }
        }
        p0 = p1 = p2 = p3 = ~0ull;
        cnt = 0;
        ull t = key[15];
#pragma unroll
        for (int mask = 1; mask < LPQ; mask <<= 1) t = min64(t, shfl_xor_u64(t, mask));
        unsigned hu = (unsigned)(t >> 32);
        unsigned fb = (hu & 0x80000000u) ? (hu & 0x7fffffffu) : ~hu;
        tau_d = (hu == 0xffffffffu) ? INFINITY : __uint_as_float(fb);
    };

    for (int t0 = 0; t0 < Npts; t0 += TS) {
        __syncthreads();
        for (int j = tid; j < TS; j += 256) {
            int i = t0 + j;
            float px = X[i * 3], py = X[i * 3 + 1], pz = X[i * 3 + 2];
            sp[j] = make_float4(px, py, pz, sumsq3(px, py, pz));
        }
        __syncthreads();
        for (int j = l; j < TS; j += LPQ) {
            float4 p = sp[j];
            float d = distf(qn, p.w, dot3fma(qx, qy, qz, p.x, p.y, p.z));
            if (d <= tau_d) {
                p3 = p2; p2 = p1; p1 = p0;
                p0 = packkey(d, t0 + j);
                ++cnt;
            }
            if (__any(cnt >= 4)) merge();
        }
    }
    if (__any(cnt > 0)) merge();

    for (int mask = 1; mask < LPQ; mask <<= 1) {
        ull ok[16];
#pragma unroll
        for (int i = 0; i < 16; ++i) ok[i] = shfl_xor_u64(key[15 - i], mask);
#pragma unroll
        for (int i = 0; i < 16; ++i) key[i] = min64(ok[i], key[i]);
#pragma unroll
        for (int dstep = 8; dstep >= 1; dstep >>= 1) {
#pragma unroll
            for (int i = 0; i < 16; ++i) {
                if (!(i & dstep)) cswap64(key[i], key[i + dstep]);
            }
        }
    }

    if (l == 0) {
        int* o = out_idx + ((size_t)b * Npts + q) * 16;
#pragma unroll
        for (int u = 0; u < 16; ++u) o[u] = (int)(unsigned)(key[u] & 0xffffffffull);
    }
}

// ---------- kernel 4: gather selected points ----------
template <int C>
__global__ void k_gather(const float* __restrict__ src_xyz, const float* __restrict__ src_feat,
                         const int* __restrict__ sel, float* __restrict__ dst_xyz,
                         float* __restrict__ dst_feat, int M, int Nsrc) {
    int b = blockIdx.y, m = blockIdx.x;
    int s = sel[(size_t)b * M + m];
    const float* fx = src_xyz + ((size_t)b * Nsrc + s) * 3;
    const float* ff = src_feat + ((size_t)b * Nsrc + s) * C;
    float* dx = dst_xyz + ((size_t)b * M + m) * 3;
    float* df = dst_feat + ((size_t)b * M + m) * C;
    if (threadIdx.x < 3) dx[threadIdx.x] = fx[threadIdx.x];
    for (int c = threadIdx.x; c < C; c += blockDim.x) df[c] = ff[c];
}

// ---------- kernel 5: fused LFA, wave-uniform row bands + scalar weights ----------
// 512 threads = 8 waves. ty = wave id (uniform) owns rows [ty*RT, ty*RT+RT).
// tx = lane = column (NCOL=64, CT=1). Weight loads are wave-uniform -> SGPR
// broadcast; B operand is one ds_read_b32/col. fma chains ascend in c
// (bit-identical to prior rounds); softmax/pool use 16-lane xor trees.
template <int CIN, int COUT>
__launch_bounds__(512)
__global__ void k_lfa(const float* __restrict__ xyz, const float* __restrict__ feat,
                      const int* __restrict__ kn,
                      const float* __restrict__ WmT, const float* __restrict__ gm, const float* __restrict__ bm,
                      const float* __restrict__ WsT,
                      const float* __restrict__ WpT, const float* __restrict__ gp, const float* __restrict__ bp,
                      float* __restrict__ outf, int Npts) {
    constexpr int NCOL = 64;
    constexpr int CR = CIN + 10;
    constexpr int PPB = NCOL / 16;           // 4 points per block
    constexpr int RT = COUT / 8;             // rows per thread (8 waves)
    constexpr int BUFR = (CR > COUT) ? CR : COUT;
    static_assert(RT % 4 == 0, "geom");
    __shared__ __align__(16) float buf[BUFR * NCOL];
    int b = blockIdx.y, tid = threadIdx.x;
    int n0 = blockIdx.x * PPB;
    const float* X = xyz + (size_t)b * Npts * 3;

    {   // ---- phase 0: build XIN[CR][NCOL] ----
        int jl = tid & 63;
        int cp = tid >> 6;
        int n = n0 + (jl >> 4);
        int k = jl & 15;
        int nbr = kn[((size_t)b * Npts + n) * 16 + k];
        const float* fr = feat + ((size_t)b * Npts + nbr) * CIN;
        for (int c = cp; c < CIN; c += 8) buf[c * NCOL + jl] = fr[c];
        if (cp == 0) {
            float cx = X[n * 3], cy = X[n * 3 + 1], cz = X[n * 3 + 2];
            float nx = X[nbr * 3], ny = X[nbr * 3 + 1], nz = X[nbr * 3 + 2];
            float dx = cx - nx, dy = cy - ny, dz = cz - nz;
            float dn = sqrtf(sumsq3(dx, dy, dz));
            buf[(CIN + 0) * NCOL + jl] = dx; buf[(CIN + 1) * NCOL + jl] = dy;
            buf[(CIN + 2) * NCOL + jl] = dz; buf[(CIN + 3) * NCOL + jl] = dn;
            buf[(CIN + 4) * NCOL + jl] = cx; buf[(CIN + 5) * NCOL + jl] = cy;
            buf[(CIN + 6) * NCOL + jl] = cz; buf[(CIN + 7) * NCOL + jl] = nx;
            buf[(CIN + 8) * NCOL + jl] = ny; buf[(CIN + 9) * NCOL + jl] = nz;
        }
    }
    __syncthreads();

    int tx = tid & 63;
    int ty = __builtin_amdgcn_readfirstlane(tid >> 6);   // wave-uniform row band

    float acc[RT];
#pragma unroll
    for (int r = 0; r < RT; ++r) acc[r] = 0.0f;

    // ---- phase 1: Wm @ XIN ----
#pragma unroll 2
    for (int c = 0; c < CR; ++c) {
        float bv = buf[c * NCOL + tx];
        const float* wr = WmT + c * COUT + ty * RT;
        float a[RT];
#pragma unroll
        for (int r4 = 0; r4 < RT; r4 += 4)
            *reinterpret_cast<float4*>(&a[r4]) =
                *reinterpret_cast<const float4*>(&wr[r4]);
#pragma unroll
        for (int r = 0; r < RT; ++r)
            acc[r] = __builtin_fmaf(a[r], bv, acc[r]);
    }
    __syncthreads();   // all XIN reads done
#pragma unroll
    for (int r = 0; r < RT; ++r) {   // bnact -> xmid into buf
        int o = ty * RT + r;
        float v = acc[r] * gm[o];
        v = v + bm[o];
        buf[o * NCOL + tx] = lrelu(v);
    }
    __syncthreads();

    // ---- phase 2: Ws @ XMID ----
    float s2[RT];
#pragma unroll
    for (int r = 0; r < RT; ++r) s2[r] = 0.0f;
#pragma unroll 2
    for (int c = 0; c < COUT; ++c) {
        float bv = buf[c * NCOL + tx];
        const float* wr = WsT + c * COUT + ty * RT;
        float a[RT];
#pragma unroll
        for (int r4 = 0; r4 < RT; r4 += 4)
            *reinterpret_cast<float4*>(&a[r4]) =
                *reinterpret_cast<const float4*>(&wr[r4]);
#pragma unroll
        for (int r = 0; r < RT; ++r)
            s2[r] = __builtin_fmaf(a[r], bv, s2[r]);
    }
    // ---- softmax over the 16 lanes of each point + attention pool ----
    float pwv[RT];
#pragma unroll
    for (int r = 0; r < RT; ++r) {
        int o = ty * RT + r;
        float m = s2[r];
        m = fmaxf(m, __shfl_xor(m, 1));
        m = fmaxf(m, __shfl_xor(m, 2));
        m = fmaxf(m, __shfl_xor(m, 4));
        m = fmaxf(m, __shfl_xor(m, 8));
        float e = expf(s2[r] - m);
        float tot = e;
        tot = tot + __shfl_xor(tot, 1);
        tot = tot + __shfl_xor(tot, 2);
        tot = tot + __shfl_xor(tot, 4);
        tot = tot + __shfl_xor(tot, 8);
        float a_ = e / tot;
        float pw = buf[o * NCOL + tx] * a_;
        pw = pw + __shfl_xor(pw, 1);
        pw = pw + __shfl_xor(pw, 2);
        pw = pw + __shfl_xor(pw, 4);
        pw = pw + __shfl_xor(pw, 8);
        pwv[r] = pw;
    }
    __syncthreads();   // all xmid reads done
    if ((tx & 15) == 0) {
        int pt = tx >> 4;
#pragma unroll
        for (int r = 0; r < RT; ++r) buf[(ty * RT + r) * PPB + pt] = pwv[r];
    }
    __syncthreads();

    // ---- phase 3: Wp @ pooled, point-major store ----
    constexpr int TPP = 512 / COUT;                 // threads per output page
    constexpr int NOUT = (PPB + TPP - 1) / TPP;
    int o = tid % COUT;
    int pbase = tid / COUT;
    float sacc[NOUT];
#pragma unroll
    for (int u = 0; u < NOUT; ++u) sacc[u] = 0.0f;
    for (int c = 0; c < COUT; ++c) {
        float wv = WpT[c * COUT + o];
#pragma unroll
        for (int u = 0; u < NOUT; ++u) {
            int p = pbase + u * TPP;
            if (p < PPB) sacc[u] = __builtin_fmaf(wv, buf[c * PPB + p], sacc[u]);
        }
    }
    float gg = gp[o], bbv = bp[o];
#pragma unroll
    for (int u = 0; u < NOUT; ++u) {
        int p = pbase + u * TPP;
        if (p < PPB) {
            float v = sacc[u] * gg;
            v = v + bbv;
            outf[((size_t)b * Npts + n0 + p) * COUT + o] = lrelu(v);
        }
    }
}

// ---------- kernel 6: candidate-parallel nearest-neighbor argmin ----------
template <int LPQ, int TS>
__launch_bounds__(256)
__global__ void k_nn_par(const float* __restrict__ tgt, const float* __restrict__ src,
                         int* __restrict__ nn, int Mt, int Ms) {
    constexpr int QPB = 256 / LPQ;
    __shared__ float4 sp[TS];
    int b = blockIdx.y;
    int tid = threadIdx.x;
    int qi = tid / LPQ;
    int l = tid % LPQ;
    int q = blockIdx.x * QPB + qi;
    const float* T = tgt + (size_t)b * Mt * 3;
    const float* S = src + (size_t)b * Ms * 3;
    float qx = T[q * 3], qy = T[q * 3 + 1], qz = T[q * 3 + 2];
    float qn = sumsq3(qx, qy, qz);
    float bd = INFINITY; int bi = 0x7fffffff;
    for (int t0 = 0; t0 < Ms; t0 += TS) {
        __syncthreads();
        for (int j = tid; j < TS; j += 256) {
            int i = t0 + j;
            float px = S[i * 3], py = S[i * 3 + 1], pz = S[i * 3 + 2];
            sp[j] = make_float4(px, py, pz, sumsq3(px, py, pz));
        }
        __syncthreads();
        for (int j = l; j < TS; j += LPQ) {
            float4 p = sp[j];
            float d = distf(qn, p.w, dot3fma(qx, qy, qz, p.x, p.y, p.z));
            if (d < bd) { bd = d; bi = t0 + j; }
        }
    }
#pragma unroll
    for (int s = LPQ / 2; s; s >>= 1) {
        float od = __shfl_xor(bd, s);
        int oi = __shfl_xor(bi, s);
        bool better = (od < bd) || ((od == bd) && (oi < bi));
        bd = better ? od : bd;
        bi = better ? oi : bi;
    }
    if (l == 0) nn[(size_t)b * Mt + q] = bi;
}

// ---------- kernel 7: up-sample + concat + dense + bn_act ----------
template <int CSRC, int CSKIP, int COUT>
__global__ void k_up(const float* __restrict__ srcf, const float* __restrict__ skipf,
                     const int* __restrict__ nn,
                     const float* __restrict__ W, const float* __restrict__ g, const float* __restrict__ bb,
                     float* __restrict__ outf, int Mt, int Ms) {
    __shared__ float fin[CSRC + CSKIP];
    int b = blockIdx.y, n = blockIdx.x, tid = threadIdx.x;
    int j = nn[(size_t)b * Mt + n];
    const float* fs = srcf + ((size_t)b * Ms + j) * CSRC;
    const float* fk = skipf + ((size_t)b * Mt + n) * CSKIP;
    for (int c = tid; c < CSRC; c += blockDim.x) fin[c] = fs[c];
    for (int c = tid; c < CSKIP; c += blockDim.x) fin[CSRC + c] = fk[c];
    __syncthreads();
    for (int o = tid; o < COUT; o += blockDim.x) {
        const float* wr = W + (size_t)o * (CSRC + CSKIP);
        float s = 0.0f;
        for (int c = 0; c < CSRC + CSKIP; ++c) s = __builtin_fmaf(wr[c], fin[c], s);
        float v = s * g[o]; v = v + bb[o];
        outf[((size_t)b * Mt + n) * COUT + o] = lrelu(v);
    }
}

// ---------- kernel 8: final up-sample + Wu1 + head fused ----------
__global__ void k_u1head(const float* __restrict__ srcf, const float* __restrict__ skipf,
                         const int* __restrict__ nn,
                         const float* __restrict__ Wu1, const float* __restrict__ gu1, const float* __restrict__ bu1,
                         const float* __restrict__ Wh1, const float* __restrict__ bh1,
                         const float* __restrict__ Wh2, const float* __restrict__ bh2,
                         float* __restrict__ out, int Mt, int Ms) {
    __shared__ float fin[192];
    __shared__ float d1[64];
    __shared__ float h[64];
    int b = blockIdx.y, n = blockIdx.x, tid = threadIdx.x;
    int j = nn[(size_t)b * Mt + n];
    const float* fs = srcf + ((size_t)b * Ms + j) * 128;
    const float* fk = skipf + ((size_t)b * Mt + n) * 64;
    for (int c = tid; c < 128; c += 64) fin[c] = fs[c];
    fin[128 + tid] = fk[tid];
    __syncthreads();
    {
        const float* wr = Wu1 + (size_t)tid * 192;
        float s = 0.0f;
        for (int c = 0; c < 192; ++c) s = __builtin_fmaf(wr[c], fin[c], s);
        float v = s * gu1[tid]; v = v + bu1[tid];
        d1[tid] = lrelu(v);
    }
    __syncthreads();
    {
        const float* wr = Wh1 + (size_t)tid * 64;
        float s = 0.0f;
        for (int c = 0; c < 64; ++c) s = __builtin_fmaf(wr[c], d1[c], s);
        float v = s + bh1[tid];
        h[tid] = lrelu(v);
    }
    __syncthreads();
    if (tid < 13) {
        const float* wr = Wh2 + (size_t)tid * 64;
        float s = 0.0f;
        for (int c = 0; c < 64; ++c) s = __builtin_fmaf(wr[c], h[c], s);
        out[((size_t)b * Mt + n) * 13 + tid] = s + bh2[tid];
    }
}

// ---------- launch ----------
extern "C" void kernel_launch(void* const* d_in, const int* in_sizes, int n_in,
                              void* d_out, int out_size, void* d_ws, size_t ws_size,
                              hipStream_t stream) {
    const float* xyz  = (const float*)d_in[0];
    const float* feat = (const float*)d_in[1];
    const int*   sel1 = (const int*)d_in[2];
    const int*   sel2 = (const int*)d_in[3];
    const float* Wpre = (const float*)d_in[4];
    const float* gpre = (const float*)d_in[5];
    const float* bpre = (const float*)d_in[6];
    const float* W1m  = (const float*)d_in[7];
    const float* g1m  = (const float*)d_in[8];
    const float* b1m  = (const float*)d_in[9];
    const float* W1s  = (const float*)d_in[10];
    const float* W1p  = (const float*)d_in[11];
    const float* g1p  = (const float*)d_in[12];
    const float* b1p  = (const float*)d_in[13];
    const float* W2m  = (const float*)d_in[14];
    const float* g2m  = (const float*)d_in[15];
    const float* b2m  = (const float*)d_in[16];
    const float* W2s  = (const float*)d_in[17];
    const float* W2p  = (const float*)d_in[18];
    const float* g2p  = (const float*)d_in[19];
    const float* b2p  = (const float*)d_in[20];
    const float* W3m  = (const float*)d_in[21];
    const float* g3m  = (const float*)d_in[22];
    const float* b3m  = (const float*)d_in[23];
    const float* W3s  = (const float*)d_in[24];
    const float* W3p  = (const float*)d_in[25];
    const float* g3p  = (const float*)d_in[26];
    const float* b3p  = (const float*)d_in[27];
    const float* Wu2  = (const float*)d_in[28];
    const float* gu2  = (const float*)d_in[29];
    const float* bu2  = (const float*)d_in[30];
    const float* Wu1  = (const float*)d_in[31];
    const float* gu1  = (const float*)d_in[32];
    const float* bu1  = (const float*)d_in[33];
    const float* Wh1  = (const float*)d_in[34];
    const float* bh1  = (const float*)d_in[35];
    const float* Wh2  = (const float*)d_in[36];
    const float* bh2  = (const float*)d_in[37];
    float* out = (float*)d_out;

    char* w = (char*)d_ws;
    auto alloc = [&](size_t n) { char* p = w; w += (n + 255) & ~(size_t)255; return p; };
    float* x0   = (float*)alloc((size_t)2 * 8192 * 64 * 4);
    float* x1   = (float*)alloc((size_t)2 * 8192 * 64 * 4);
    float* f1   = (float*)alloc((size_t)2 * 4096 * 64 * 4);
    float* x2   = (float*)alloc((size_t)2 * 4096 * 128 * 4);
    float* f2   = (float*)alloc((size_t)2 * 2048 * 128 * 4);
    float* x3   = (float*)alloc((size_t)2 * 2048 * 256 * 4);
    float* d2f  = (float*)alloc((size_t)2 * 4096 * 128 * 4);
    float* xyz1 = (float*)alloc((size_t)2 * 4096 * 3 * 4);
    float* xyz2 = (float*)alloc((size_t)2 * 2048 * 3 * 4);
    int* n0   = (int*)alloc((size_t)2 * 8192 * 16 * 4);
    int* n1   = (int*)alloc((size_t)2 * 4096 * 16 * 4);
    int* n2   = (int*)alloc((size_t)2 * 2048 * 16 * 4);
    int* nnu2 = (int*)alloc((size_t)2 * 4096 * 4);
    int* nnu1 = (int*)alloc((size_t)2 * 8192 * 4);
    float* WmT1 = (float*)alloc((size_t)74 * 64 * 4);
    float* WsT1 = (float*)alloc((size_t)64 * 64 * 4);
    float* WpT1 = (float*)alloc((size_t)64 * 64 * 4);
    float* WmT2 = (float*)alloc((size_t)74 * 128 * 4);
    float* WsT2 = (float*)alloc((size_t)128 * 128 * 4);
    float* WpT2 = (float*)alloc((size_t)128 * 128 * 4);
    float* WmT3 = (float*)alloc((size_t)138 * 256 * 4);
    float* WsT3 = (float*)alloc((size_t)256 * 256 * 4);
    float* WpT3 = (float*)alloc((size_t)256 * 256 * 4);

    k_pre<<<128, 128, 0, stream>>>(feat, Wpre, gpre, bpre, x0);
    k_wt<<<(64 * 74 + 255) / 256, 256, 0, stream>>>(W1m, WmT1, 64, 74);
    k_wt<<<(64 * 64 + 255) / 256, 256, 0, stream>>>(W1s, WsT1, 64, 64);
    k_wt<<<(64 * 64 + 255) / 256, 256, 0, stream>>>(W1p, WpT1, 64, 64);
    k_wt<<<(128 * 74 + 255) / 256, 256, 0, stream>>>(W2m, WmT2, 128, 74);
    k_wt<<<(128 * 128 + 255) / 256, 256, 0, stream>>>(W2s, WsT2, 128, 128);
    k_wt<<<(128 * 128 + 255) / 256, 256, 0, stream>>>(W2p, WpT2, 128, 128);
    k_wt<<<(256 * 138 + 255) / 256, 256, 0, stream>>>(W3m, WmT3, 256, 138);
    k_wt<<<(256 * 256 + 255) / 256, 256, 0, stream>>>(W3s, WsT3, 256, 256);
    k_wt<<<(256 * 256 + 255) / 256, 256, 0, stream>>>(W3p, WpT3, 256, 256);

    // ---- level 1 ----
    k_knn_reg<32, 1024><<<dim3(1024, 2), 256, 0, stream>>>(xyz, n0, 8192);
    k_lfa<64, 64><<<dim3(8192 / 4, 2), 512, 0, stream>>>(
        xyz, x0, n0, WmT1, g1m, b1m, WsT1, WpT1, g1p, b1p, x1, 8192);

    // ---- level 2 ----
    k_gather<64><<<dim3(4096, 2), 64, 0, stream>>>(xyz, x1, sel1, xyz1, f1, 4096, 8192);
    k_knn_reg<32, 1024><<<dim3(512, 2), 256, 0, stream>>>(xyz1, n1, 4096);
    k_lfa<64, 128><<<dim3(4096 / 4, 2), 512, 0, stream>>>(
        xyz1, f1, n1, WmT2, g2m, b2m, WsT2, WpT2, g2p, b2p, x2, 4096);

    // ---- level 3 ----
    k_gather<128><<<dim3(2048, 2), 64, 0, stream>>>(xyz1, x2, sel2, xyz2, f2, 2048, 4096);
    k_knn_reg<32, 1024><<<dim3(256, 2), 256, 0, stream>>>(xyz2, n2, 2048);
    k_lfa<128, 256><<<dim3(2048 / 4, 2), 512, 0, stream>>>(
        xyz2, f2, n2, WmT3, g3m, b3m, WsT3, WpT3, g3p, b3p, x3, 2048);

    // ---- decoder ----
    k_nn_par<16, 512><<<dim3(256, 2), 256, 0, stream>>>(xyz1, xyz2, nnu2, 4096, 2048);
    k_up<256, 128, 128><<<dim3(4096, 2), 128, 0, stream>>>(x3, x2, nnu2, Wu2, gu2, bu2,
                                                           d2f, 4096, 2048);
    k_nn_par<16, 512><<<dim3(512, 2), 256, 0, stream>>>(xyz, xyz1, nnu1, 8192, 4096);
    k_u1head<<<dim3(8192, 2), 64, 0, stream>>>(d2f, x1, nnu1, Wu1, gu1, bu1, Wh1, bh1,
                                               Wh2, bh2, out, 8192, 4096);
}

// Round 12
// 1052.834 us; speedup vs baseline: 1.1749x; 1.1749x over previous
//
#include <hip/hip_runtime.h>
#include <hip/hip_bf16.h>

#pragma clang fp contract(off)

typedef unsigned long long ull;

// ---------- numeric helpers (rounding-faithful to reference) ----------
__device__ __forceinline__ float lrelu(float v) { return v >= 0.0f ? v : 0.1f * v; }

__device__ __forceinline__ float sumsq3(float x, float y, float z) {
    return ((x * x) + (y * y)) + (z * z);
}

__device__ __forceinline__ float dot3fma(float ax, float ay, float az,
                                         float bx, float by, float bz) {
    float d = ax * bx;
    d = __builtin_fmaf(ay, by, d);
    d = __builtin_fmaf(az, bz, d);
    return d;
}

// d = (qn+sn) - 2*dot with one rounding (2*dot exact) == fma(-2, dot, s)
__device__ __forceinline__ float distf(float qn, float sn, float dot) {
    float s = qn + sn;
    return __builtin_fmaf(-2.0f, dot, s);
}

// monotone key: integer compare on key == lexicographic (d, idx) compare
__device__ __forceinline__ ull packkey(float d, int i) {
    unsigned u = __float_as_uint(d);
    u = (u & 0x80000000u) ? ~u : (u | 0x80000000u);
    return ((ull)u << 32) | (unsigned)i;
}

__device__ __forceinline__ ull shfl_xor_u64(ull v, int mask) {
    int lo = __shfl_xor((int)(v & 0xffffffffull), mask);
    int hi = __shfl_xor((int)(v >> 32), mask);
    return ((ull)(unsigned)hi << 32) | (unsigned)lo;
}

__device__ __forceinline__ void cswap64(ull& x, ull& y) {
    bool sw = y < x;
    ull lo = sw ? y : x;
    ull hi = sw ? x : y;
    x = lo; y = hi;
}

__device__ __forceinline__ ull min64(ull a, ull b) { return a < b ? a : b; }

// ---------- kernel 1: pre-MLP ----------
__global__ void k_pre(const float* __restrict__ feat, const float* __restrict__ W,
                      const float* __restrict__ g, const float* __restrict__ bb,
                      float* __restrict__ x0) {
    int p = blockIdx.x * blockDim.x + threadIdx.x;
    if (p >= 2 * 8192) return;
    const float* f = feat + (size_t)p * 6;
    float fv[6];
#pragma unroll
    for (int c = 0; c < 6; ++c) fv[c] = f[c];
    float* out = x0 + (size_t)p * 64;
    for (int o = 0; o < 64; ++o) {
        float s = 0.0f;
#pragma unroll
        for (int c = 0; c < 6; ++c) s = __builtin_fmaf(W[o * 6 + c], fv[c], s);
        float v = s * g[o];
        v = v + bb[o];
        out[o] = lrelu(v);
    }
}

// ---------- kernel 2: all 9 weight transposes in one launch ----------
__global__ void k_wt_all(const float* __restrict__ s0, const float* __restrict__ s1,
                         const float* __restrict__ s2, const float* __restrict__ s3,
                         const float* __restrict__ s4, const float* __restrict__ s5,
                         const float* __restrict__ s6, const float* __restrict__ s7,
                         const float* __restrict__ s8,
                         float* __restrict__ d0, float* __restrict__ d1,
                         float* __restrict__ d2, float* __restrict__ d3,
                         float* __restrict__ d4, float* __restrict__ d5,
                         float* __restrict__ d6, float* __restrict__ d7,
                         float* __restrict__ d8) {
    const int Ms[9] = {64, 64, 64, 128, 128, 128, 256, 256, 256};
    const int Ks[9] = {74, 64, 64, 74, 128, 128, 138, 256, 256};
    const float* S[9] = {s0, s1, s2, s3, s4, s5, s6, s7, s8};
    float* D[9] = {d0, d1, d2, d3, d4, d5, d6, d7, d8};
    int seg = blockIdx.y;
    int M = Ms[seg], K = Ks[seg];
    int i = blockIdx.x * 256 + threadIdx.x;
    if (i >= M * K) return;
    int o = i / K, c = i - o * K;
    D[seg][c * M + o] = S[seg][i];
}

// ---------- kernel 3: KNN via pending-buffer + exact tau pruning ----------
template <int LPQ, int TS>
__launch_bounds__(256)
__global__ void k_knn_reg(const float* __restrict__ xyz, int* __restrict__ out_idx, int Npts) {
    constexpr int QPB = 256 / LPQ;
    __shared__ float4 sp[TS];
    int b = blockIdx.y;
    int tid = threadIdx.x;
    int qi = tid / LPQ;
    int l = tid % LPQ;
    int q = blockIdx.x * QPB + qi;
    const float* X = xyz + (size_t)b * Npts * 3;
    float qx = X[q * 3], qy = X[q * 3 + 1], qz = X[q * 3 + 2];
    float qn = sumsq3(qx, qy, qz);

    ull key[16];
#pragma unroll
    for (int u = 0; u < 16; ++u) key[u] = ~0ull;
    ull p0 = ~0ull, p1 = ~0ull, p2 = ~0ull, p3 = ~0ull;
    int cnt = 0;
    float tau_d = INFINITY;

    auto merge = [&]() {
        cswap64(p0, p2); cswap64(p1, p3); cswap64(p0, p1);
        cswap64(p2, p3); cswap64(p1, p2);
        key[12] = min64(key[12], p3);
        key[13] = min64(key[13], p2);
        key[14] = min64(key[14], p1);
        key[15] = min64(key[15], p0);
#pragma unroll
        for (int dstep = 8; dstep >= 1; dstep >>= 1) {
#pragma unroll
            for (int i = 0; i < 16; ++i) {
                if (!(i & dstep)) cswap64(key[i], key[i + dstep]);
            }
        }
        p0 = p1 = p2 = p3 = ~0ull;
        cnt = 0;
        ull t = key[15];
#pragma unroll
        for (int mask = 1; mask < LPQ; mask <<= 1) t = min64(t, shfl_xor_u64(t, mask));
        unsigned hu = (unsigned)(t >> 32);
        unsigned fb = (hu & 0x80000000u) ? (hu & 0x7fffffffu) : ~hu;
        tau_d = (hu == 0xffffffffu) ? INFINITY : __uint_as_float(fb);
    };

    for (int t0 = 0; t0 < Npts; t0 += TS) {
        __syncthreads();
        for (int j = tid; j < TS; j += 256) {
            int i = t0 + j;
            float px = X[i * 3], py = X[i * 3 + 1], pz = X[i * 3 + 2];
            sp[j] = make_float4(px, py, pz, sumsq3(px, py, pz));
        }
        __syncthreads();
        for (int j = l; j < TS; j += LPQ) {
            float4 p = sp[j];
            float d = distf(qn, p.w, dot3fma(qx, qy, qz, p.x, p.y, p.z));
            if (d <= tau_d) {
                p3 = p2; p2 = p1; p1 = p0;
                p0 = packkey(d, t0 + j);
                ++cnt;
            }
            if (__any(cnt >= 4)) merge();
        }
    }
    if (__any(cnt > 0)) merge();

    for (int mask = 1; mask < LPQ; mask <<= 1) {
        ull ok[16];
#pragma unroll
        for (int i = 0; i < 16; ++i) ok[i] = shfl_xor_u64(key[15 - i], mask);
#pragma unroll
        for (int i = 0; i < 16; ++i) key[i] = min64(ok[i], key[i]);
#pragma unroll
        for (int dstep = 8; dstep >= 1; dstep >>= 1) {
#pragma unroll
            for (int i = 0; i < 16; ++i) {
                if (!(i & dstep)) cswap64(key[i], key[i + dstep]);
            }
        }
    }

    if (l == 0) {
        int* o = out_idx + ((size_t)b * Npts + q) * 16;
#pragma unroll
        for (int u = 0; u < 16; ++u) o[u] = (int)(unsigned)(key[u] & 0xffffffffull);
    }
}

// ---------- kernel 4: gather selected points ----------
template <int C>
__global__ void k_gather(const float* __restrict__ src_xyz, const float* __restrict__ src_feat,
                         const int* __restrict__ sel, float* __restrict__ dst_xyz,
                         float* __restrict__ dst_feat, int M, int Nsrc) {
    int b = blockIdx.y, m = blockIdx.x;
    int s = sel[(size_t)b * M + m];
    const float* fx = src_xyz + ((size_t)b * Nsrc + s) * 3;
    const float* ff = src_feat + ((size_t)b * Nsrc + s) * C;
    float* dx = dst_xyz + ((size_t)b * M + m) * 3;
    float* df = dst_feat + ((size_t)b * M + m) * C;
    if (threadIdx.x < 3) dx[threadIdx.x] = fx[threadIdx.x];
    for (int c = threadIdx.x; c < C; c += blockDim.x) df[c] = ff[c];
}

// ---------- kernel 5: fused LFA (R8 body, THREADS-parametric row bands) ----------
// BANDS = THREADS/16 row bands (ty), 16 column slots (tx) x CT cols each.
// RT = COUT/BANDS. 512-thread variants double waves/SIMD at same 64 KB LDS.
// All fma chains ascend in c; softmax trees identical to round-8 -> bit-identical.
template <int CIN, int COUT, int NCOL, int THREADS>
__launch_bounds__(THREADS)
__global__ void k_lfa(const float* __restrict__ xyz, const float* __restrict__ feat,
                      const int* __restrict__ kn,
                      const float* __restrict__ WmT, const float* __restrict__ gm, const float* __restrict__ bm,
                      const float* __restrict__ WsT,
                      const float* __restrict__ WpT, const float* __restrict__ gp, const float* __restrict__ bp,
                      float* __restrict__ outf, int Npts) {
    constexpr int CR = CIN + 10;
    constexpr int PPB = NCOL / 16;
    constexpr int BANDS = THREADS / 16;
    constexpr int RT = COUT / BANDS;
    constexpr int CT = NCOL / 16;
    constexpr int TPG = 16 / CT;
    constexpr int BUFR = (CR > COUT) ? CR : COUT;
    static_assert(RT % 4 == 0 && CT % 4 == 0, "geom");
    __shared__ __align__(16) float buf[BUFR * NCOL];
    int b = blockIdx.y, tid = threadIdx.x;
    int n0 = blockIdx.x * PPB;
    const float* X = xyz + (size_t)b * Npts * 3;

    {   // ---- phase 0: build XIN ----
        constexpr int TPC = THREADS / NCOL;
        int jl = tid % NCOL;
        int cp = tid / NCOL;
        int n = n0 + (jl >> 4);
        int k = jl & 15;
        int nbr = kn[((size_t)b * Npts + n) * 16 + k];
        const float* fr = feat + ((size_t)b * Npts + nbr) * CIN;
        for (int c = cp; c < CIN; c += TPC) buf[c * NCOL + jl] = fr[c];
        if (cp == 0) {
            float cx = X[n * 3], cy = X[n * 3 + 1], cz = X[n * 3 + 2];
            float nx = X[nbr * 3], ny = X[nbr * 3 + 1], nz = X[nbr * 3 + 2];
            float dx = cx - nx, dy = cy - ny, dz = cz - nz;
            float dn = sqrtf(sumsq3(dx, dy, dz));
            buf[(CIN + 0) * NCOL + jl] = dx; buf[(CIN + 1) * NCOL + jl] = dy;
            buf[(CIN + 2) * NCOL + jl] = dz; buf[(CIN + 3) * NCOL + jl] = dn;
            buf[(CIN + 4) * NCOL + jl] = cx; buf[(CIN + 5) * NCOL + jl] = cy;
            buf[(CIN + 6) * NCOL + jl] = cz; buf[(CIN + 7) * NCOL + jl] = nx;
            buf[(CIN + 8) * NCOL + jl] = ny; buf[(CIN + 9) * NCOL + jl] = nz;
        }
    }
    __syncthreads();

    int tx = tid & 15, ty = tid >> 4;
    float acc[RT][CT];

    auto loadA = [&](float* a, const float* WT, int c) {
#pragma unroll
        for (int r4 = 0; r4 < RT; r4 += 4)
            *reinterpret_cast<float4*>(&a[r4]) =
                *reinterpret_cast<const float4*>(&WT[c * COUT + ty * RT + r4]);
    };
    auto loadB = [&](float* bv, int c) {
#pragma unroll
        for (int c4 = 0; c4 < CT; c4 += 4)
            *reinterpret_cast<float4*>(&bv[c4]) =
                *reinterpret_cast<const float4*>(&buf[c * NCOL + tx * CT + c4]);
    };

    // ---- phase 1: Wm @ XIN ----
#pragma unroll
    for (int r = 0; r < RT; ++r)
#pragma unroll
        for (int cc = 0; cc < CT; ++cc) acc[r][cc] = 0.0f;
    for (int c = 0; c < CR; ++c) {
        float a[RT], bv[CT];
        loadA(a, WmT, c); loadB(bv, c);
#pragma unroll
        for (int r = 0; r < RT; ++r)
#pragma unroll
            for (int cc = 0; cc < CT; ++cc)
                acc[r][cc] = __builtin_fmaf(a[r], bv[cc], acc[r][cc]);
    }
    __syncthreads();   // all XIN reads done
#pragma unroll
    for (int r = 0; r < RT; ++r) {   // bnact -> xmid into buf
        int o = ty * RT + r;
        float gg = gm[o], bbv = bm[o];
        float vv[CT];
#pragma unroll
        for (int cc = 0; cc < CT; ++cc) {
            float v = acc[r][cc] * gg;
            v = v + bbv;
            vv[cc] = lrelu(v);
        }
#pragma unroll
        for (int c4 = 0; c4 < CT; c4 += 4)
            *reinterpret_cast<float4*>(&buf[o * NCOL + tx * CT + c4]) =
                *reinterpret_cast<const float4*>(&vv[c4]);
    }
    __syncthreads();

    // ---- phase 2: Ws @ XMID + softmax + pool ----
#pragma unroll
    for (int r = 0; r < RT; ++r)
#pragma unroll
        for (int cc = 0; cc < CT; ++cc) acc[r][cc] = 0.0f;
    for (int c = 0; c < COUT; ++c) {
        float a[RT], bv[CT];
        loadA(a, WsT, c); loadB(bv, c);
#pragma unroll
        for (int r = 0; r < RT; ++r)
#pragma unroll
            for (int cc = 0; cc < CT; ++cc)
                acc[r][cc] = __builtin_fmaf(a[r], bv[cc], acc[r][cc]);
    }
    float pwv[RT];
#pragma unroll
    for (int r = 0; r < RT; ++r) {
        int o = ty * RT + r;
        float m = acc[r][0];
#pragma unroll
        for (int cc = 1; cc < CT; ++cc) m = fmaxf(m, acc[r][cc]);
#pragma unroll
        for (int mask = 1; mask < TPG; mask <<= 1) m = fmaxf(m, __shfl_xor(m, mask));
        float e[CT]; float ps = 0.0f;
#pragma unroll
        for (int cc = 0; cc < CT; ++cc) { e[cc] = expf(acc[r][cc] - m); ps = ps + e[cc]; }
        float tot = ps;
#pragma unroll
        for (int mask = 1; mask < TPG; mask <<= 1) tot = tot + __shfl_xor(tot, mask);
        float xm[CT];
#pragma unroll
        for (int c4 = 0; c4 < CT; c4 += 4)
            *reinterpret_cast<float4*>(&xm[c4]) =
                *reinterpret_cast<const float4*>(&buf[o * NCOL + tx * CT + c4]);
        float pw = 0.0f;
#pragma unroll
        for (int cc = 0; cc < CT; ++cc) {
            float a_ = e[cc] / tot;
            float t = xm[cc] * a_;
            pw = pw + t;
        }
#pragma unroll
        for (int mask = 1; mask < TPG; mask <<= 1) pw = pw + __shfl_xor(pw, mask);
        pwv[r] = pw;
    }
    __syncthreads();   // all xmid reads done
    if (tx % TPG == 0) {
        int pt = tx / TPG;
#pragma unroll
        for (int r = 0; r < RT; ++r) buf[(ty * RT + r) * PPB + pt] = pwv[r];
    }
    __syncthreads();

    // ---- phase 3: Wp @ pooled, point-major store ----
    constexpr int TPP = THREADS / COUT;
    constexpr int NOUT = (PPB + TPP - 1) / TPP;
    int o = tid % COUT;
    int pbase = tid / COUT;
    float sacc[NOUT];
#pragma unroll
    for (int u = 0; u < NOUT; ++u) sacc[u] = 0.0f;
    for (int c = 0; c < COUT; ++c) {
        float wv = WpT[c * COUT + o];
#pragma unroll
        for (int u = 0; u < NOUT; ++u) {
            int p = pbase + u * TPP;
            if (p < PPB) sacc[u] = __builtin_fmaf(wv, buf[c * PPB + p], sacc[u]);
        }
    }
    float gg = gp[o], bbv = bp[o];
#pragma unroll
    for (int u = 0; u < NOUT; ++u) {
        int p = pbase + u * TPP;
        if (p < PPB) {
            float v = sacc[u] * gg;
            v = v + bbv;
            outf[((size_t)b * Npts + n0 + p) * COUT + o] = lrelu(v);
        }
    }
}

// ---------- kernel 6: candidate-parallel nearest-neighbor argmin ----------
template <int LPQ, int TS>
__launch_bounds__(256)
__global__ void k_nn_par(const float* __restrict__ tgt, const float* __restrict__ src,
                         int* __restrict__ nn, int Mt, int Ms) {
    constexpr int QPB = 256 / LPQ;
    __shared__ float4 sp[TS];
    int b = blockIdx.y;
    int tid = threadIdx.x;
    int qi = tid / LPQ;
    int l = tid % LPQ;
    int q = blockIdx.x * QPB + qi;
    const float* T = tgt + (size_t)b * Mt * 3;
    const float* S = src + (size_t)b * Ms * 3;
    float qx = T[q * 3], qy = T[q * 3 + 1], qz = T[q * 3 + 2];
    float qn = sumsq3(qx, qy, qz);
    float bd = INFINITY; int bi = 0x7fffffff;
    for (int t0 = 0; t0 < Ms; t0 += TS) {
        __syncthreads();
        for (int j = tid; j < TS; j += 256) {
            int i = t0 + j;
            float px = S[i * 3], py = S[i * 3 + 1], pz = S[i * 3 + 2];
            sp[j] = make_float4(px, py, pz, sumsq3(px, py, pz));
        }
        __syncthreads();
        for (int j = l; j < TS; j += LPQ) {
            float4 p = sp[j];
            float d = distf(qn, p.w, dot3fma(qx, qy, qz, p.x, p.y, p.z));
            if (d < bd) { bd = d; bi = t0 + j; }
        }
    }
#pragma unroll
    for (int s = LPQ / 2; s; s >>= 1) {
        float od = __shfl_xor(bd, s);
        int oi = __shfl_xor(bi, s);
        bool better = (od < bd) || ((od == bd) && (oi < bi));
        bd = better ? od : bd;
        bi = better ? oi : bi;
    }
    if (l == 0) nn[(size_t)b * Mt + q] = bi;
}

// ---------- kernel 7: up-sample + concat + dense (4 points/block, weight reuse) ----------
template <int CSRC, int CSKIP, int COUT, int PTS>
__global__ void k_up(const float* __restrict__ srcf, const float* __restrict__ skipf,
                     const int* __restrict__ nn,
                     const float* __restrict__ W, const float* __restrict__ g, const float* __restrict__ bb,
                     float* __restrict__ outf, int Mt, int Ms) {
    constexpr int CTOT = CSRC + CSKIP;
    __shared__ float fin[PTS][CTOT];
    int b = blockIdx.y, tid = threadIdx.x;
    int n0 = blockIdx.x * PTS;
#pragma unroll
    for (int pp = 0; pp < PTS; ++pp) {
        int n = n0 + pp;
        int j = nn[(size_t)b * Mt + n];
        const float* fs = srcf + ((size_t)b * Ms + j) * CSRC;
        const float* fk = skipf + ((size_t)b * Mt + n) * CSKIP;
        for (int c = tid; c < CSRC; c += COUT) fin[pp][c] = fs[c];
        for (int c = tid; c < CSKIP; c += COUT) fin[pp][CSRC + c] = fk[c];
    }
    __syncthreads();
    int o = tid;   // blockDim.x == COUT
    const float* wr = W + (size_t)o * CTOT;
    float s[PTS];
#pragma unroll
    for (int pp = 0; pp < PTS; ++pp) s[pp] = 0.0f;
    for (int c = 0; c < CTOT; ++c) {
        float wv = wr[c];
#pragma unroll
        for (int pp = 0; pp < PTS; ++pp)
            s[pp] = __builtin_fmaf(wv, fin[pp][c], s[pp]);
    }
    float gg = g[o], bbv = bb[o];
#pragma unroll
    for (int pp = 0; pp < PTS; ++pp) {
        float v = s[pp] * gg;
        v = v + bbv;
        outf[((size_t)b * Mt + n0 + pp) * COUT + o] = lrelu(v);
    }
}

// ---------- kernel 8: final up-sample + Wu1 + head fused (4 points/block) ----------
__global__ void k_u1head(const float* __restrict__ srcf, const float* __restrict__ skipf,
                         const int* __restrict__ nn,
                         const float* __restrict__ Wu1, const float* __restrict__ gu1, const float* __restrict__ bu1,
                         const float* __restrict__ Wh1, const float* __restrict__ bh1,
                         const float* __restrict__ Wh2, const float* __restrict__ bh2,
                         float* __restrict__ out, int Mt, int Ms) {
    __shared__ float fin[4][192];
    __shared__ float d1[4][64];
    __shared__ float h[4][64];
    int b = blockIdx.y, tid = threadIdx.x;   // 64 threads
    int n0 = blockIdx.x * 4;
#pragma unroll
    for (int pp = 0; pp < 4; ++pp) {
        int n = n0 + pp;
        int j = nn[(size_t)b * Mt + n];
        const float* fs = srcf + ((size_t)b * Ms + j) * 128;
        const float* fk = skipf + ((size_t)b * Mt + n) * 64;
        for (int c = tid; c < 128; c += 64) fin[pp][c] = fs[c];
        fin[pp][128 + tid] = fk[tid];
    }
    __syncthreads();
    {
        const float* wr = Wu1 + (size_t)tid * 192;
        float s[4] = {0.0f, 0.0f, 0.0f, 0.0f};
        for (int c = 0; c < 192; ++c) {
            float wv = wr[c];
#pragma unroll
            for (int pp = 0; pp < 4; ++pp)
                s[pp] = __builtin_fmaf(wv, fin[pp][c], s[pp]);
        }
        float gg = gu1[tid], bbv = bu1[tid];
#pragma unroll
        for (int pp = 0; pp < 4; ++pp) {
            float v = s[pp] * gg;
            v = v + bbv;
            d1[pp][tid] = lrelu(v);
        }
    }
    __syncthreads();
    {
        const float* wr = Wh1 + (size_t)tid * 64;
        float s[4] = {0.0f, 0.0f, 0.0f, 0.0f};
        for (int c = 0; c < 64; ++c) {
            float wv = wr[c];
#pragma unroll
            for (int pp = 0; pp < 4; ++pp)
                s[pp] = __builtin_fmaf(wv, d1[pp][c], s[pp]);
        }
        float bbv = bh1[tid];
#pragma unroll
        for (int pp = 0; pp < 4; ++pp) {
            float v = s[pp] + bbv;
            h[pp][tid] = lrelu(v);
        }
    }
    __syncthreads();
    if (tid < 13) {
        const float* wr = Wh2 + (size_t)tid * 64;
        float s[4] = {0.0f, 0.0f, 0.0f, 0.0f};
        for (int c = 0; c < 64; ++c) {
            float wv = wr[c];
#pragma unroll
            for (int pp = 0; pp < 4; ++pp)
                s[pp] = __builtin_fmaf(wv, h[pp][c], s[pp]);
        }
        float bbv = bh2[tid];
#pragma unroll
        for (int pp = 0; pp < 4; ++pp)
            out[((size_t)b * Mt + n0 + pp) * 13 + tid] = s[pp] + bbv;
    }
}

// ---------- launch ----------
extern "C" void kernel_launch(void* const* d_in, const int* in_sizes, int n_in,
                              void* d_out, int out_size, void* d_ws, size_t ws_size,
                              hipStream_t stream) {
    const float* xyz  = (const float*)d_in[0];
    const float* feat = (const float*)d_in[1];
    const int*   sel1 = (const int*)d_in[2];
    const int*   sel2 = (const int*)d_in[3];
    const float* Wpre = (const float*)d_in[4];
    const float* gpre = (const float*)d_in[5];
    const float* bpre = (const float*)d_in[6];
    const float* W1m  = (const float*)d_in[7];
    const float* g1m  = (const float*)d_in[8];
    const float* b1m  = (const float*)d_in[9];
    const float* W1s  = (const float*)d_in[10];
    const float* W1p  = (const float*)d_in[11];
    const float* g1p  = (const float*)d_in[12];
    const float* b1p  = (const float*)d_in[13];
    const float* W2m  = (const float*)d_in[14];
    const float* g2m  = (const float*)d_in[15];
    const float* b2m  = (const float*)d_in[16];
    const float* W2s  = (const float*)d_in[17];
    const float* W2p  = (const float*)d_in[18];
    const float* g2p  = (const float*)d_in[19];
    const float* b2p  = (const float*)d_in[20];
    const float* W3m  = (const float*)d_in[21];
    const float* g3m  = (const float*)d_in[22];
    const float* b3m  = (const float*)d_in[23];
    const float* W3s  = (const float*)d_in[24];
    const float* W3p  = (const float*)d_in[25];
    const float* g3p  = (const float*)d_in[26];
    const float* b3p  = (const float*)d_in[27];
    const float* Wu2  = (const float*)d_in[28];
    const float* gu2  = (const float*)d_in[29];
    const float* bu2  = (const float*)d_in[30];
    const float* Wu1  = (const float*)d_in[31];
    const float* gu1  = (const float*)d_in[32];
    const float* bu1  = (const float*)d_in[33];
    const float* Wh1  = (const float*)d_in[34];
    const float* bh1  = (const float*)d_in[35];
    const float* Wh2  = (const float*)d_in[36];
    const float* bh2  = (const float*)d_in[37];
    float* out = (float*)d_out;

    char* w = (char*)d_ws;
    auto alloc = [&](size_t n) { char* p = w; w += (n + 255) & ~(size_t)255; return p; };
    float* x0   = (float*)alloc((size_t)2 * 8192 * 64 * 4);
    float* x1   = (float*)alloc((size_t)2 * 8192 * 64 * 4);
    float* f1   = (float*)alloc((size_t)2 * 4096 * 64 * 4);
    float* x2   = (float*)alloc((size_t)2 * 4096 * 128 * 4);
    float* f2   = (float*)alloc((size_t)2 * 2048 * 128 * 4);
    float* x3   = (float*)alloc((size_t)2 * 2048 * 256 * 4);
    float* d2f  = (float*)alloc((size_t)2 * 4096 * 128 * 4);
    float* xyz1 = (float*)alloc((size_t)2 * 4096 * 3 * 4);
    float* xyz2 = (float*)alloc((size_t)2 * 2048 * 3 * 4);
    int* n0   = (int*)alloc((size_t)2 * 8192 * 16 * 4);
    int* n1   = (int*)alloc((size_t)2 * 4096 * 16 * 4);
    int* n2   = (int*)alloc((size_t)2 * 2048 * 16 * 4);
    int* nnu2 = (int*)alloc((size_t)2 * 4096 * 4);
    int* nnu1 = (int*)alloc((size_t)2 * 8192 * 4);
    float* WmT1 = (float*)alloc((size_t)74 * 64 * 4);
    float* WsT1 = (float*)alloc((size_t)64 * 64 * 4);
    float* WpT1 = (float*)alloc((size_t)64 * 64 * 4);
    float* WmT2 = (float*)alloc((size_t)74 * 128 * 4);
    float* WsT2 = (float*)alloc((size_t)128 * 128 * 4);
    float* WpT2 = (float*)alloc((size_t)128 * 128 * 4);
    float* WmT3 = (float*)alloc((size_t)138 * 256 * 4);
    float* WsT3 = (float*)alloc((size_t)256 * 256 * 4);
    float* WpT3 = (float*)alloc((size_t)256 * 256 * 4);

    k_pre<<<128, 128, 0, stream>>>(feat, Wpre, gpre, bpre, x0);
    k_wt_all<<<dim3(256, 9), 256, 0, stream>>>(W1m, W1s, W1p, W2m, W2s, W2p, W3m, W3s, W3p,
                                               WmT1, WsT1, WpT1, WmT2, WsT2, WpT2,
                                               WmT3, WsT3, WpT3);

    // ---- level 1 ----
    k_knn_reg<32, 1024><<<dim3(1024, 2), 256, 0, stream>>>(xyz, n0, 8192);
    k_lfa<64, 64, 128, 256><<<dim3(8192 / 8, 2), 256, 0, stream>>>(
        xyz, x0, n0, WmT1, g1m, b1m, WsT1, WpT1, g1p, b1p, x1, 8192);

    // ---- level 2 ----
    k_gather<64><<<dim3(4096, 2), 64, 0, stream>>>(xyz, x1, sel1, xyz1, f1, 4096, 8192);
    k_knn_reg<32, 1024><<<dim3(512, 2), 256, 0, stream>>>(xyz1, n1, 4096);
    k_lfa<64, 128, 128, 512><<<dim3(4096 / 8, 2), 512, 0, stream>>>(
        xyz1, f1, n1, WmT2, g2m, b2m, WsT2, WpT2, g2p, b2p, x2, 4096);

    // ---- level 3 ----
    k_gather<128><<<dim3(2048, 2), 64, 0, stream>>>(xyz1, x2, sel2, xyz2, f2, 2048, 4096);
    k_knn_reg<32, 1024><<<dim3(256, 2), 256, 0, stream>>>(xyz2, n2, 2048);
    k_lfa<128, 256, 64, 512><<<dim3(2048 / 4, 2), 512, 0, stream>>>(
        xyz2, f2, n2, WmT3, g3m, b3m, WsT3, WpT3, g3p, b3p, x3, 2048);

    // ---- decoder ----
    k_nn_par<16, 512><<<dim3(256, 2), 256, 0, stream>>>(xyz1, xyz2, nnu2, 4096, 2048);
    k_up<256, 128, 128, 4><<<dim3(1024, 2), 128, 0, stream>>>(x3, x2, nnu2, Wu2, gu2, bu2,
                                                              d2f, 4096, 2048);
    k_nn_par<16, 512><<<dim3(512, 2), 256, 0, stream>>>(xyz, xyz1, nnu1, 8192, 4096);
    k_u1head<<<dim3(2048, 2), 64, 0, stream>>>(d2f, x1, nnu1, Wu1, gu1, bu1, Wh1, bh1,
                                               Wh2, bh2, out, 8192, 4096);
}